// Round 25
// baseline (168.687 us; speedup 1.0000x reference)
//
#include <hip/hip_runtime.h>
#include <hip/hip_bf16.h>

// Triangle attention, S=384, D=128, H=4, HD=32.
// k0 weight-cast (W2/o_w stored FRAGMENT-MAJOR) -> k1 LN + bias(+mask, fragment-major)
// -> k2 qkv+g GEMM (512thr BM=128, XCD-swizzled, B from global/L1, As-only LDS, (512,3))
// -> k3 attention (r24 winner: 3 qtiles/wave, K+V LDS, bias pipelined, (512,3))
// -> k4 gate+out GEMM (512thr BM=128, B from global/L1, As-only LDS, (512,3)).
//
// Fragment-major layout: for each MFMA fragment (16 rows x 16B per lane-slot), the 64
// lane-slots are stored contiguously: block_base + lane*16. Wave reads are contiguous
// 1024B (conflict-free in LDS, single-burst coalesced in global).
//   Q,K per (b,h): [tile 0..23][lane=16g+lr]*16B  holds row=tile*16+lr, cols 8g..8g+7
//   V  per (b,h): [ktile64 0..11][dt 0..1][lane=16G+R]*16B holds d=dt*16+R,
//                  k=ktile64*32+16*(j>>2)+4G+(j&3)
//   bias per h:   [qtile][ktile][lane]*16B f32x4: q=qtile*16+lr, k=ktile*16+4g+i
//   W2f/o_wbf:    [row-tile][ks][lane=16g+lr]*16B holds row=tile*16+lr, col ks*32+8g..+7
// Weights-from-global rationale: W2 (128KB) / o_wb (32KB) are L1/L2-hot and shared by all
// waves + co-XCD blocks; dropping the B LDS tile halves k2/k4 LDS to 34.8KB -> 3 blocks/CU
// (the same min-blocks lever that won r24 for k3: 64.4 -> 56.4us).
// k3 failed probes: ones-MFMA (r14), full unroll (r15), K-global (r16), 256thr (r17),
// O-store staging (r19), 6-chain ILP (r23). NOTE: raw inline-asm v_exp_f32 is WRONG
// (TRANS hazard; r9). NOTE: k1+k2 fusion LOST 18us (r11, barrier drains).
// C/D layout (HW-verified): col = lane&15, row = 4*(lane>>4) + reg.

#define S_ 384
#define D_ 128
#define MTOT (S_*S_)

typedef __bf16 bf16;
typedef __bf16 bf16x8 __attribute__((ext_vector_type(8)));
typedef __bf16 bf16x4 __attribute__((ext_vector_type(4)));
typedef float  f32x4  __attribute__((ext_vector_type(4)));

#define LOG2E      1.4426950408889634f
#define QSCALE     0.17677669529663687f       // 1/sqrt(32)
#define QSCALE_L2E 0.25505008455121566f       // QSCALE * LOG2E

#if defined(__has_builtin)
#  if __has_builtin(__builtin_amdgcn_exp2f)
#    define HAVE_EXP2 1
#  else
#    define HAVE_EXP2 0
#  endif
#else
#  define HAVE_EXP2 0
#endif

#if HAVE_EXP2
#  define BIAS_MUL LOG2E
#  define Q_MUL    QSCALE_L2E
__device__ __forceinline__ float fast_pexp(float x) { return __builtin_amdgcn_exp2f(x); }
#else
#  define BIAS_MUL 1.0f
#  define Q_MUL    QSCALE
__device__ __forceinline__ float fast_pexp(float x) { return __expf(x); }
#endif

// ---------------- workspace layout (bytes) ----------------
#define OFF_LN   0u            // bf16 [147456][128]  (reused as o_ws after k2)
#define OFF_Q    37748736u     // bf16 fragment-major, 24576 B per (b,h)  (pre-scaled)
#define OFF_K    75497472u     // bf16 fragment-major, 24576 B per (b,h)
#define OFF_V    113246208u    // bf16 fragment-major, 24576 B per (b,h)
#define OFF_G    150994944u    // bf16 [147456][128]
#define OFF_BIAS 188743680u    // f32 fragment-major, 24*24*1024 B per h
#define OFF_W2   191102976u    // bf16 [512][128] fragment-major (32 tiles x 4096B)
#define OFF_OWB  191234048u    // bf16 [128][128] fragment-major (8 tiles x 4096B)

// fragment-major weight address (bf16 index) for element (row n, col c), cols 0..127
__device__ __forceinline__ int wfrag_idx(int n, int c) {
    return (n >> 4) * 2048 + (c >> 5) * 512 + (16 * ((c >> 3) & 3) + (n & 15)) * 8 + (c & 7);
}

// ---------------- k0: cast weights to bf16 (fragment-major) ----------------
__global__ __launch_bounds__(256) void k0_convert(const float* __restrict__ qkv_w,
                                                  const float* __restrict__ g_w,
                                                  const float* __restrict__ o_w,
                                                  bf16* __restrict__ W2,
                                                  bf16* __restrict__ o_wb) {
    int idx = blockIdx.x * 256 + threadIdx.x;
    if (idx < 512 * 128) {
        float v = (idx < 384 * 128) ? qkv_w[idx] : g_w[idx - 384 * 128];
        W2[wfrag_idx(idx >> 7, idx & 127)] = (bf16)v;
    }
    int idx2 = idx - 512 * 128;
    if (idx2 >= 0 && idx2 < 128 * 128)
        o_wb[wfrag_idx(idx2 >> 7, idx2 & 127)] = (bf16)o_w[idx2];
}

// ---------------- k1: LayerNorm (fp32) + triangle-bias projection (+mask fold) ----------------
// 2 positions per wave; bias written fragment-major (times BIAS_MUL).
__global__ __launch_bounds__(256) void k1_ln(const float* __restrict__ x,
                                             const float* __restrict__ ln_w,
                                             const float* __restrict__ ln_b,
                                             const float* __restrict__ bias_w,
                                             const float* __restrict__ mask,
                                             bf16* __restrict__ ln_ws,
                                             float* __restrict__ bias_f) {
    int wid = threadIdx.x >> 6, lane = threadIdx.x & 63;
    int grp = lane >> 5, sub = lane & 31;
    int pos = blockIdx.x * 8 + wid * 2 + grp;    // [0, 147456)
    f32x4 v = ((const f32x4*)(x + (size_t)pos * D_))[sub];
    float sum = v[0] + v[1] + v[2] + v[3];
    float ssq = v[0]*v[0] + v[1]*v[1] + v[2]*v[2] + v[3]*v[3];
    #pragma unroll
    for (int off = 16; off; off >>= 1) {
        sum += __shfl_xor(sum, off);
        ssq += __shfl_xor(ssq, off);
    }
    float mu   = sum * (1.0f / D_);
    float var  = ssq * (1.0f / D_) - mu * mu;
    float rstd = rsqrtf(var + 1e-5f);
    f32x4 w4 = ((const f32x4*)ln_w)[sub];
    f32x4 b4 = ((const f32x4*)ln_b)[sub];
    f32x4 y;
    #pragma unroll
    for (int i = 0; i < 4; ++i) y[i] = (v[i] - mu) * rstd * w4[i] + b4[i];
    bf16x4 yb;
    #pragma unroll
    for (int i = 0; i < 4; ++i) yb[i] = (bf16)y[i];
    *(bf16x4*)(ln_ws + (size_t)pos * D_ + 4 * sub) = yb;

    int ii = pos / S_, jj = pos - ii * S_;
    float mk = mask[jj];
    float p[4];
    #pragma unroll
    for (int h = 0; h < 4; ++h) {
        f32x4 bw = ((const f32x4*)(bias_w + h * D_))[sub];
        p[h] = y[0]*bw[0] + y[1]*bw[1] + y[2]*bw[2] + y[3]*bw[3];
    }
    #pragma unroll
    for (int off = 16; off; off >>= 1)
        #pragma unroll
        for (int h = 0; h < 4; ++h) p[h] += __shfl_xor(p[h], off);
    if (sub == 0) {
        // fragment-major: [h][qtile][ktile][((k>>2)&3)*16 + (q&15)] f32x4, elem k&3
        int base = ((ii >> 4) * 24 + (jj >> 4)) * 256 + (((jj >> 2) & 3) * 16 + (ii & 15)) * 4 + (jj & 3);
        #pragma unroll
        for (int h = 0; h < 4; ++h)
            bias_f[h * 147456 + base] = (p[h] + mk) * BIAS_MUL;
    }
}

// ---------------- k2: [147456,128] @ W2^T -> q (pre-scaled),k,v (fragment-major) / g ----------------
// 512 threads, BM=128. B fragments read straight from fragment-major W2 (global, L1-hot);
// LDS holds only As (34.8KB, aliased by C-tile) -> 3 blocks/CU with (512,3).
// Block id swizzle: the 4 n-chunk blocks sharing an A-tile land on one XCD.
__global__ __launch_bounds__(512, 3) void k2_proj(const bf16* __restrict__ ln_ws,
                                                  const bf16* __restrict__ W2,
                                                  bf16* __restrict__ q_ws,
                                                  bf16* __restrict__ k_ws,
                                                  bf16* __restrict__ v_ws,
                                                  bf16* __restrict__ g_ws) {
    __shared__ __align__(16) char smem[128 * 272];
    char* As = smem;                 // [128][272B]
    char* Cs = smem;                 // C-tile aliases As (dead after compute)
    int t = threadIdx.x;
    int bid = blockIdx.x;
    int xcd = bid & 7;
    int rem = bid >> 3;
    int by  = rem & 3;               // n-chunk: 0=Q 1=K 2=V 3=G
    int bx  = ((rem >> 2) << 3) + xcd;
    int m0 = bx * 128;
    #pragma unroll
    for (int it = 0; it < 4; ++it) {
        int byte = it * 8192 + t * 16;
        int row = byte >> 8, colb = byte & 255;
        *(int4*)(As + row * 272 + colb) = *(const int4*)((const char*)ln_ws + (size_t)(m0 + row) * 256 + colb);
    }
    __syncthreads();
    int wid = t >> 6, lane = t & 63, lr = lane & 15, g = lane >> 4;
    int wm = wid >> 1, wn = wid & 1;          // 8 waves: 4x2 grid of 32x64 tiles
    const char* wbase = (const char*)W2 + (size_t)(by * 8 + wn * 4) * 4096 + lane * 16;
    f32x4 acc[2][4] = {};
    #pragma unroll
    for (int ks = 0; ks < 4; ++ks) {
        bf16x8 af[2], bfr[4];
        #pragma unroll
        for (int mt = 0; mt < 2; ++mt)
            af[mt] = *(const bf16x8*)(As + (wm * 32 + mt * 16 + lr) * 272 + ks * 64 + g * 16);
        #pragma unroll
        for (int nt = 0; nt < 4; ++nt)
            bfr[nt] = *(const bf16x8*)(wbase + nt * 4096 + ks * 1024);
        #pragma unroll
        for (int mt = 0; mt < 2; ++mt)
            #pragma unroll
            for (int nt = 0; nt < 4; ++nt)
                acc[mt][nt] = __builtin_amdgcn_mfma_f32_16x16x32_bf16(af[mt], bfr[nt], acc[mt][nt], 0, 0, 0);
    }
    __syncthreads();   // all LDS reads done; safe to overwrite As with C-tile
    float cmul = (by == 0) ? Q_MUL : 1.0f;    // fold score scaling into Q (f32)
    #pragma unroll
    for (int mt = 0; mt < 2; ++mt)
        #pragma unroll
        for (int nt = 0; nt < 4; ++nt)
            #pragma unroll
            for (int i = 0; i < 4; ++i) {
                int ml = wm * 32 + mt * 16 + g * 4 + i;
                int nl = wn * 64 + nt * 16 + lr;
                *(bf16*)(Cs + ml * 272 + nl * 2) = (bf16)(acc[mt][nt][i] * cmul);
            }
    __syncthreads();
    int b = m0 / 384;                // 128 | 384 -> single i per block
    int jj0 = m0 - b * 384;
    if (by < 2) {
        // Q/K: wave (h = wid>>1, half = wid&1); 4 fragments: ds_read_b128 + coalesced store
        bf16* dst0 = (by == 0) ? q_ws : k_ws;
        int h = wid >> 1, thalf = wid & 1;
        size_t bh = (size_t)b * 4 + h;
        bf16* dst = dst0 + bh * 12288 + (size_t)((jj0 >> 4) + thalf * 4) * 512 + lane * 8;
        #pragma unroll
        for (int tl = 0; tl < 4; ++tl) {
            bf16x8 v8 = *(const bf16x8*)(Cs + (thalf * 64 + tl * 16 + lr) * 272 + (h * 32 + 8 * g) * 2);
            *(bf16x8*)(dst + tl * 512) = v8;
        }
    } else if (by == 2) {
        // V: wave (h = wid>>1, vhalf = wid&1); 4 fragments (kt64 x dt): 8 LDS reads + store
        int h = wid >> 1, vhalf = wid & 1;
        size_t bh = (size_t)b * 4 + h;
        bf16* dst = v_ws + bh * 12288 + (size_t)(jj0 >> 5) * 1024 + lane * 8;
        #pragma unroll
        for (int f = 0; f < 4; ++f) {
            int kt64 = vhalf * 2 + (f >> 1), dt = f & 1;
            bf16x8 v8;
            #pragma unroll
            for (int j = 0; j < 8; ++j) {
                int kl = 16 * (j >> 2) + 4 * g + (j & 3);
                v8[j] = *(const bf16*)(Cs + (kt64 * 32 + kl) * 272 + (h * 32 + dt * 16 + lr) * 2);
            }
            *(bf16x8*)(dst + kt64 * 1024 + dt * 512) = v8;
        }
    } else {
        // G: vectorized copy [128][256B]
        #pragma unroll
        for (int j = 0; j < 4; ++j) {
            int byte = j * 8192 + t * 16;
            int ml = byte >> 8, col = byte & 255;
            *(int4*)((char*)g_ws + (size_t)(m0 + ml) * 256 + col) = *(const int4*)(Cs + ml * 272 + col);
        }
    }
}

// ---------------- k3: attention, one block (512 thr) per (b,h), 3 qtiles per wave ----------------
// r24 winner: K+V in LDS, 3 independent QK->exp->PV chains per wave, bias as MFMA C
// operand software-pipelined one tt ahead, direct O-stores, launch_bounds (512,3).
__global__ __launch_bounds__(512, 3) void k3_attn(const bf16* __restrict__ q_ws,
                                                  const bf16* __restrict__ k_ws,
                                                  const bf16* __restrict__ v_ws,
                                                  const float* __restrict__ bias_f,
                                                  bf16* __restrict__ o_ws) {
    __shared__ __align__(16) char smem[49152];
    char* Ksh = smem;                // 24 ktiles x 1024B, fragment-major
    char* Vsh = smem + 24576;        // 12 ktile64 x 2 dt x 1024B, fragment-major
    int t = threadIdx.x;
    int bh = blockIdx.x;
    int b = bh >> 2, h = bh & 3;
    const char* kbase = (const char*)(k_ws + (size_t)bh * 12288);
    const char* vbase = (const char*)(v_ws + (size_t)bh * 12288);
    #pragma unroll
    for (int it = 0; it < 3; ++it) {
        int byte = it * 8192 + t * 16;
        *(int4*)(Ksh + byte) = *(const int4*)(kbase + byte);
        *(int4*)(Vsh + byte) = *(const int4*)(vbase + byte);
    }
    __syncthreads();
    int wid = t >> 6, lane = t & 63, lr = lane & 15, g = lane >> 4;
    const char* qbase = (const char*)(q_ws + (size_t)bh * 12288);
    const float* bbase = bias_f + (size_t)h * 147456;
    bf16x8 qf[3];
    const f32x4* bp[3];
    #pragma unroll
    for (int u = 0; u < 3; ++u) {
        int qtile = wid + u * 8;
        qf[u] = *(const bf16x8*)(qbase + qtile * 1024 + lane * 16);
        bp[u] = (const f32x4*)(bbase + qtile * 6144) + lane;   // [ktile][lane] f32x4
    }
    // prime the bias pipeline (ktiles 0,1)
    f32x4 bcur[3][2];
    #pragma unroll
    for (int u = 0; u < 3; ++u) {
        bcur[u][0] = bp[u][0];
        bcur[u][1] = bp[u][64];
    }
    f32x4 oa[3][2] = {};
    float lsum[3] = {0.f, 0.f, 0.f};
    #pragma unroll 1
    for (int kt = 0; kt < 4; ++kt) {
        #pragma unroll
        for (int tt = 0; tt < 3; ++tt) {
            int k0t = kt * 6 + tt * 2;
            // prefetch next tt's bias (final iteration reads <=2KB past bias into W2
            // region — allocated workspace, value discarded)
            int knext = k0t + 2;
            f32x4 bnext[3][2];
            #pragma unroll
            for (int u = 0; u < 3; ++u) {
                bnext[u][0] = bp[u][knext * 64];
                bnext[u][1] = bp[u][(knext + 1) * 64];
            }
            bf16x8 kf0 = *(const bf16x8*)(Ksh + k0t * 1024 + lane * 16);
            bf16x8 kf1 = *(const bf16x8*)(Ksh + (k0t + 1) * 1024 + lane * 16);
            bf16x8 pf[3];
            #pragma unroll
            for (int u = 0; u < 3; ++u) {
                f32x4 a0 = __builtin_amdgcn_mfma_f32_16x16x32_bf16(kf0, qf[u], bcur[u][0], 0, 0, 0);
                f32x4 a1 = __builtin_amdgcn_mfma_f32_16x16x32_bf16(kf1, qf[u], bcur[u][1], 0, 0, 0);
                #pragma unroll
                for (int i = 0; i < 4; ++i) {
                    float p0 = fast_pexp(a0[i]);
                    float p1 = fast_pexp(a1[i]);
                    lsum[u] += p0 + p1;
                    pf[u][i]     = (bf16)p0;
                    pf[u][4 + i] = (bf16)p1;
                }
            }
            const char* vb = Vsh + (kt * 3 + tt) * 2048 + lane * 16;
            bf16x8 vf0 = *(const bf16x8*)(vb);
            bf16x8 vf1 = *(const bf16x8*)(vb + 1024);
            #pragma unroll
            for (int u = 0; u < 3; ++u) {
                oa[u][0] = __builtin_amdgcn_mfma_f32_16x16x32_bf16(pf[u], vf0, oa[u][0], 0, 0, 0);
                oa[u][1] = __builtin_amdgcn_mfma_f32_16x16x32_bf16(pf[u], vf1, oa[u][1], 0, 0, 0);
            }
            #pragma unroll
            for (int u = 0; u < 3; ++u) {
                bcur[u][0] = bnext[u][0];
                bcur[u][1] = bnext[u][1];
            }
        }
    }
    #pragma unroll
    for (int u = 0; u < 3; ++u) {
        float l = lsum[u];
        l += __shfl_xor(l, 16);
        l += __shfl_xor(l, 32);
        float inv = 1.0f / l;
        float invq[4];
        #pragma unroll
        for (int i = 0; i < 4; ++i) invq[i] = __shfl(inv, 4 * g + i);
        int q0 = (wid + u * 8) * 16;
        #pragma unroll
        for (int dt = 0; dt < 2; ++dt)
            #pragma unroll
            for (int i = 0; i < 4; ++i)
                o_ws[((size_t)b * 384 + q0 + 4 * g + i) * 128 + h * 32 + dt * 16 + lr] = (bf16)(oa[u][dt][i] * invq[i]);
    }
}

// ---------------- k4: out = (o * sigmoid(g)) @ o_w^T, 512 thr BM=128, B from global ----------------
__global__ __launch_bounds__(512, 3) void k4_out(const bf16* __restrict__ o_ws,
                                                 const bf16* __restrict__ g_ws,
                                                 const bf16* __restrict__ o_wb,
                                                 float* __restrict__ out) {
    __shared__ __align__(16) char smem[128 * 272];
    char* As = smem;
    int t = threadIdx.x;
    int m0 = blockIdx.x * 128;
    #pragma unroll
    for (int it = 0; it < 4; ++it) {
        int byte = it * 8192 + t * 16;
        int row = byte >> 8, colb = byte & 255;
        bf16x8 o8 = *(const bf16x8*)((const char*)o_ws + (size_t)(m0 + row) * 256 + colb);
        bf16x8 g8 = *(const bf16x8*)((const char*)g_ws + (size_t)(m0 + row) * 256 + colb);
        bf16x8 a8;
        #pragma unroll
        for (int j = 0; j < 8; ++j) {
            float ov = (float)o8[j], gv = (float)g8[j];
            a8[j] = (bf16)(ov / (1.0f + __expf(-gv)));
        }
        *(bf16x8*)(As + row * 272 + colb) = a8;
    }
    __syncthreads();
    int wid = t >> 6, lane = t & 63, lr = lane & 15, g = lane >> 4;
    int wm = wid >> 1, wn = wid & 1;          // 8 waves: 4x2 grid of 32x64 tiles
    const char* wbase = (const char*)o_wb + (size_t)(wn * 4) * 4096 + lane * 16;
    f32x4 acc[2][4] = {};
    #pragma unroll
    for (int ks = 0; ks < 4; ++ks) {
        bf16x8 af[2], bfr[4];
        #pragma unroll
        for (int mt = 0; mt < 2; ++mt)
            af[mt] = *(const bf16x8*)(As + (wm * 32 + mt * 16 + lr) * 272 + ks * 64 + g * 16);
        #pragma unroll
        for (int nt = 0; nt < 4; ++nt)
            bfr[nt] = *(const bf16x8*)(wbase + nt * 4096 + ks * 1024);
        #pragma unroll
        for (int mt = 0; mt < 2; ++mt)
            #pragma unroll
            for (int nt = 0; nt < 4; ++nt)
                acc[mt][nt] = __builtin_amdgcn_mfma_f32_16x16x32_bf16(af[mt], bfr[nt], acc[mt][nt], 0, 0, 0);
    }
    #pragma unroll
    for (int mt = 0; mt < 2; ++mt)
        #pragma unroll
        for (int nt = 0; nt < 4; ++nt)
            #pragma unroll
            for (int i = 0; i < 4; ++i) {
                int m = m0 + wm * 32 + mt * 16 + g * 4 + i;
                int n = wn * 64 + nt * 16 + lr;
                out[(size_t)m * 128 + n] = acc[mt][nt][i];
            }
}

extern "C" void kernel_launch(void* const* d_in, const int* in_sizes, int n_in,
                              void* d_out, int out_size, void* d_ws, size_t ws_size,
                              hipStream_t stream) {
    const float* x      = (const float*)d_in[0];
    const float* mask   = (const float*)d_in[1];
    const float* ln_w   = (const float*)d_in[2];
    const float* ln_b   = (const float*)d_in[3];
    const float* bias_w = (const float*)d_in[4];
    const float* qkv_w  = (const float*)d_in[5];
    const float* g_w    = (const float*)d_in[6];
    const float* o_w    = (const float*)d_in[7];
    char* ws = (char*)d_ws;
    bf16*  ln_ws  = (bf16*)(ws + OFF_LN);
    bf16*  q_ws   = (bf16*)(ws + OFF_Q);
    bf16*  k_ws   = (bf16*)(ws + OFF_K);
    bf16*  v_ws   = (bf16*)(ws + OFF_V);
    bf16*  g_ws   = (bf16*)(ws + OFF_G);
    float* bias_f = (float*)(ws + OFF_BIAS);
    bf16*  W2     = (bf16*)(ws + OFF_W2);
    bf16*  o_wb   = (bf16*)(ws + OFF_OWB);
    bf16*  o_ws   = ln_ws;   // alias: ln dead after k2
    float* out    = (float*)d_out;

    k0_convert<<<dim3(320), dim3(256), 0, stream>>>(qkv_w, g_w, o_w, W2, o_wb);
    k1_ln<<<dim3(MTOT / 8), dim3(256), 0, stream>>>(x, ln_w, ln_b, bias_w, mask, ln_ws, bias_f);
    k2_proj<<<dim3(MTOT / 128 * 4), dim3(512), 0, stream>>>(ln_ws, W2, q_ws, k_ws, v_ws, g_ws);
    k3_attn<<<dim3(S_ * 4), dim3(512), 0, stream>>>(q_ws, k_ws, v_ws, bias_f, o_ws);
    k4_out<<<dim3(MTOT / 128), dim3(512), 0, stream>>>(o_ws, g_ws, o_wb, out);
}

// Round 26
// 160.673 us; speedup vs baseline: 1.0499x; 1.0499x over previous
//
#include <hip/hip_runtime.h>
#include <hip/hip_bf16.h>

// Triangle attention, S=384, D=128, H=4, HD=32.  (ROUND-24 BEST CONFIGURATION — reverted
// from r25's B-from-global experiment which lost 3.5us on k2/k4.)
// k0 weight-cast -> k1 LN + bias(+mask, fragment-major) -> k2 qkv+g GEMM (512thr BM=128,
// XCD-swizzled, A+B in LDS, (512,2)) -> k3 attention (3 qtiles/wave, K+V LDS, bias
// software-pipelined 1 tt ahead, exp2 builtin, direct O-stores, (512,3) -> 3 blocks/CU)
// -> k4 gate+out GEMM (512thr BM=128, (512,2)).
//
// Fragment-major layout: for each MFMA fragment (16 rows x 16B per lane-slot), the 64
// lane-slots are stored contiguously: block_base + lane*16. Wave reads are contiguous
// 1024B (conflict-free in LDS, single-burst coalesced in global).
//   Q,K per (b,h): [tile 0..23][lane=16g+lr]*16B  holds row=tile*16+lr, cols 8g..8g+7
//   V  per (b,h): [ktile64 0..11][dt 0..1][lane=16G+R]*16B holds d=dt*16+R,
//                  k=ktile64*32+16*(j>>2)+4G+(j&3)
//   bias per h:   [qtile][ktile][lane]*16B f32x4: q=qtile*16+lr, k=ktile*16+4g+i
// Session ledger (k3): ones-MFMA (r14 -11us), full unroll (r15 -12us), K-global (r16 -8us),
// 256thr split (r17 -8us), O-store staging (r19 -30us), 6-chain ILP (r23, VGPR 196),
// bias prefetch (r20, neutral; kept), (512,3) min-blocks (r24, -8us WIN).
// k2/k4: B-from-global (r25, -3.5us total, reverted). k1+k2 fusion (r11, -18us).
// NOTE: raw inline-asm v_exp_f32 is WRONG (TRANS forwarding hazard; r9). Builtin only.
// C/D layout (HW-verified): col = lane&15, row = 4*(lane>>4) + reg.

#define S_ 384
#define D_ 128
#define MTOT (S_*S_)

typedef __bf16 bf16;
typedef __bf16 bf16x8 __attribute__((ext_vector_type(8)));
typedef __bf16 bf16x4 __attribute__((ext_vector_type(4)));
typedef float  f32x4  __attribute__((ext_vector_type(4)));

#define LOG2E      1.4426950408889634f
#define QSCALE     0.17677669529663687f       // 1/sqrt(32)
#define QSCALE_L2E 0.25505008455121566f       // QSCALE * LOG2E

#if defined(__has_builtin)
#  if __has_builtin(__builtin_amdgcn_exp2f)
#    define HAVE_EXP2 1
#  else
#    define HAVE_EXP2 0
#  endif
#else
#  define HAVE_EXP2 0
#endif

#if HAVE_EXP2
#  define BIAS_MUL LOG2E
#  define Q_MUL    QSCALE_L2E
__device__ __forceinline__ float fast_pexp(float x) { return __builtin_amdgcn_exp2f(x); }
#else
#  define BIAS_MUL 1.0f
#  define Q_MUL    QSCALE
__device__ __forceinline__ float fast_pexp(float x) { return __expf(x); }
#endif

// ---------------- workspace layout (bytes) ----------------
#define OFF_LN   0u            // bf16 [147456][128]  (reused as o_ws after k2)
#define OFF_Q    37748736u     // bf16 fragment-major, 24576 B per (b,h)  (pre-scaled)
#define OFF_K    75497472u     // bf16 fragment-major, 24576 B per (b,h)
#define OFF_V    113246208u    // bf16 fragment-major, 24576 B per (b,h)
#define OFF_G    150994944u    // bf16 [147456][128]
#define OFF_BIAS 188743680u    // f32 fragment-major, 24*24*1024 B per h
#define OFF_W2   191102976u    // bf16 [512][128]
#define OFF_OWB  191234048u    // bf16 [128][128]

// ---------------- k0: cast weights to bf16 ----------------
__global__ __launch_bounds__(256) void k0_convert(const float* __restrict__ qkv_w,
                                                  const float* __restrict__ g_w,
                                                  const float* __restrict__ o_w,
                                                  bf16* __restrict__ W2,
                                                  bf16* __restrict__ o_wb) {
    int idx = blockIdx.x * 256 + threadIdx.x;
    if (idx < 512 * 128) {
        float v = (idx < 384 * 128) ? qkv_w[idx] : g_w[idx - 384 * 128];
        W2[idx] = (bf16)v;
    }
    int idx2 = idx - 512 * 128;
    if (idx2 >= 0 && idx2 < 128 * 128) o_wb[idx2] = (bf16)o_w[idx2];
}

// ---------------- k1: LayerNorm (fp32) + triangle-bias projection (+mask fold) ----------------
// 2 positions per wave; bias written fragment-major (times BIAS_MUL).
__global__ __launch_bounds__(256) void k1_ln(const float* __restrict__ x,
                                             const float* __restrict__ ln_w,
                                             const float* __restrict__ ln_b,
                                             const float* __restrict__ bias_w,
                                             const float* __restrict__ mask,
                                             bf16* __restrict__ ln_ws,
                                             float* __restrict__ bias_f) {
    int wid = threadIdx.x >> 6, lane = threadIdx.x & 63;
    int grp = lane >> 5, sub = lane & 31;
    int pos = blockIdx.x * 8 + wid * 2 + grp;    // [0, 147456)
    f32x4 v = ((const f32x4*)(x + (size_t)pos * D_))[sub];
    float sum = v[0] + v[1] + v[2] + v[3];
    float ssq = v[0]*v[0] + v[1]*v[1] + v[2]*v[2] + v[3]*v[3];
    #pragma unroll
    for (int off = 16; off; off >>= 1) {
        sum += __shfl_xor(sum, off);
        ssq += __shfl_xor(ssq, off);
    }
    float mu   = sum * (1.0f / D_);
    float var  = ssq * (1.0f / D_) - mu * mu;
    float rstd = rsqrtf(var + 1e-5f);
    f32x4 w4 = ((const f32x4*)ln_w)[sub];
    f32x4 b4 = ((const f32x4*)ln_b)[sub];
    f32x4 y;
    #pragma unroll
    for (int i = 0; i < 4; ++i) y[i] = (v[i] - mu) * rstd * w4[i] + b4[i];
    bf16x4 yb;
    #pragma unroll
    for (int i = 0; i < 4; ++i) yb[i] = (bf16)y[i];
    *(bf16x4*)(ln_ws + (size_t)pos * D_ + 4 * sub) = yb;

    int ii = pos / S_, jj = pos - ii * S_;
    float mk = mask[jj];
    float p[4];
    #pragma unroll
    for (int h = 0; h < 4; ++h) {
        f32x4 bw = ((const f32x4*)(bias_w + h * D_))[sub];
        p[h] = y[0]*bw[0] + y[1]*bw[1] + y[2]*bw[2] + y[3]*bw[3];
    }
    #pragma unroll
    for (int off = 16; off; off >>= 1)
        #pragma unroll
        for (int h = 0; h < 4; ++h) p[h] += __shfl_xor(p[h], off);
    if (sub == 0) {
        // fragment-major: [h][qtile][ktile][((k>>2)&3)*16 + (q&15)] f32x4, elem k&3
        int base = ((ii >> 4) * 24 + (jj >> 4)) * 256 + (((jj >> 2) & 3) * 16 + (ii & 15)) * 4 + (jj & 3);
        #pragma unroll
        for (int h = 0; h < 4; ++h)
            bias_f[h * 147456 + base] = (p[h] + mk) * BIAS_MUL;
    }
}

// ---------------- k2: [147456,128] @ W2^T -> q (pre-scaled),k,v (fragment-major) / g ----------------
// 512 threads, BM=128. Block id swizzle: bid = x + 8*(by + 4*G), bx = 8G+x -> the 4 n-chunk
// blocks sharing an A-tile all have bid%8 == x (same XCD under round-robin dispatch).
// Epilogue staged through LDS (C-tile aliases dead A-tile): coalesced vector stores only.
__global__ __launch_bounds__(512, 2) void k2_proj(const bf16* __restrict__ ln_ws,
                                                  const bf16* __restrict__ W2,
                                                  bf16* __restrict__ q_ws,
                                                  bf16* __restrict__ k_ws,
                                                  bf16* __restrict__ v_ws,
                                                  bf16* __restrict__ g_ws) {
    __shared__ __align__(16) char smem[128 * 272 + 128 * 272];
    char* As = smem;                 // [128][272B]
    char* Bs = smem + 128 * 272;     // [128][272B]
    char* Cs = smem;                 // [128][272B] C-tile, aliases As (dead after compute)
    int t = threadIdx.x;
    int bid = blockIdx.x;
    int xcd = bid & 7;
    int rem = bid >> 3;
    int by  = rem & 3;               // n-chunk: 0=Q 1=K 2=V 3=G
    int bx  = ((rem >> 2) << 3) + xcd;
    int m0 = bx * 128;
    int n0 = by * 128;
    #pragma unroll
    for (int it = 0; it < 4; ++it) {
        int byte = it * 8192 + t * 16;
        int row = byte >> 8, colb = byte & 255;
        *(int4*)(As + row * 272 + colb) = *(const int4*)((const char*)ln_ws + (size_t)(m0 + row) * 256 + colb);
    }
    #pragma unroll
    for (int it = 0; it < 4; ++it) {
        int byte = it * 8192 + t * 16;
        int row = byte >> 8, colb = byte & 255;
        *(int4*)(Bs + row * 272 + colb) = *(const int4*)((const char*)W2 + (size_t)(n0 + row) * 256 + colb);
    }
    __syncthreads();
    int wid = t >> 6, lane = t & 63, lr = lane & 15, g = lane >> 4;
    int wm = wid >> 1, wn = wid & 1;          // 8 waves: 4x2 grid of 32x64 tiles
    f32x4 acc[2][4] = {};
    #pragma unroll
    for (int ks = 0; ks < 4; ++ks) {
        bf16x8 af[2], bfr[4];
        #pragma unroll
        for (int mt = 0; mt < 2; ++mt)
            af[mt] = *(const bf16x8*)(As + (wm * 32 + mt * 16 + lr) * 272 + ks * 64 + g * 16);
        #pragma unroll
        for (int nt = 0; nt < 4; ++nt)
            bfr[nt] = *(const bf16x8*)(Bs + (wn * 64 + nt * 16 + lr) * 272 + ks * 64 + g * 16);
        #pragma unroll
        for (int mt = 0; mt < 2; ++mt)
            #pragma unroll
            for (int nt = 0; nt < 4; ++nt)
                acc[mt][nt] = __builtin_amdgcn_mfma_f32_16x16x32_bf16(af[mt], bfr[nt], acc[mt][nt], 0, 0, 0);
    }
    __syncthreads();   // all LDS reads done; safe to overwrite As with C-tile
    float cmul = (by == 0) ? Q_MUL : 1.0f;    // fold score scaling into Q (f32)
    #pragma unroll
    for (int mt = 0; mt < 2; ++mt)
        #pragma unroll
        for (int nt = 0; nt < 4; ++nt)
            #pragma unroll
            for (int i = 0; i < 4; ++i) {
                int ml = wm * 32 + mt * 16 + g * 4 + i;
                int nl = wn * 64 + nt * 16 + lr;
                *(bf16*)(Cs + ml * 272 + nl * 2) = (bf16)(acc[mt][nt][i] * cmul);
            }
    __syncthreads();
    int b = m0 / 384;                // 128 | 384 -> single i per block
    int jj0 = m0 - b * 384;
    if (by < 2) {
        // Q/K: wave (h = wid>>1, half = wid&1); 4 fragments: ds_read_b128 + coalesced store
        bf16* dst0 = (by == 0) ? q_ws : k_ws;
        int h = wid >> 1, thalf = wid & 1;
        size_t bh = (size_t)b * 4 + h;
        bf16* dst = dst0 + bh * 12288 + (size_t)((jj0 >> 4) + thalf * 4) * 512 + lane * 8;
        #pragma unroll
        for (int tl = 0; tl < 4; ++tl) {
            bf16x8 v8 = *(const bf16x8*)(Cs + (thalf * 64 + tl * 16 + lr) * 272 + (h * 32 + 8 * g) * 2);
            *(bf16x8*)(dst + tl * 512) = v8;
        }
    } else if (by == 2) {
        // V: wave (h = wid>>1, vhalf = wid&1); 4 fragments (kt64 x dt): 8 LDS reads + store
        int h = wid >> 1, vhalf = wid & 1;
        size_t bh = (size_t)b * 4 + h;
        bf16* dst = v_ws + bh * 12288 + (size_t)(jj0 >> 5) * 1024 + lane * 8;
        #pragma unroll
        for (int f = 0; f < 4; ++f) {
            int kt64 = vhalf * 2 + (f >> 1), dt = f & 1;
            bf16x8 v8;
            #pragma unroll
            for (int j = 0; j < 8; ++j) {
                int kl = 16 * (j >> 2) + 4 * g + (j & 3);
                v8[j] = *(const bf16*)(Cs + (kt64 * 32 + kl) * 272 + (h * 32 + dt * 16 + lr) * 2);
            }
            *(bf16x8*)(dst + kt64 * 1024 + dt * 512) = v8;
        }
    } else {
        // G: vectorized copy [128][256B]
        #pragma unroll
        for (int j = 0; j < 4; ++j) {
            int byte = j * 8192 + t * 16;
            int ml = byte >> 8, col = byte & 255;
            *(int4*)((char*)g_ws + (size_t)(m0 + ml) * 256 + col) = *(const int4*)(Cs + ml * 272 + col);
        }
    }
}

// ---------------- k3: attention, one block (512 thr) per (b,h), 3 qtiles per wave ----------------
// r24 winner: K+V in LDS, 3 independent QK->exp->PV chains per wave, bias as MFMA C
// operand software-pipelined one tt ahead, direct O-stores, launch_bounds (512,3).
__global__ __launch_bounds__(512, 3) void k3_attn(const bf16* __restrict__ q_ws,
                                                  const bf16* __restrict__ k_ws,
                                                  const bf16* __restrict__ v_ws,
                                                  const float* __restrict__ bias_f,
                                                  bf16* __restrict__ o_ws) {
    __shared__ __align__(16) char smem[49152];
    char* Ksh = smem;                // 24 ktiles x 1024B, fragment-major
    char* Vsh = smem + 24576;        // 12 ktile64 x 2 dt x 1024B, fragment-major
    int t = threadIdx.x;
    int bh = blockIdx.x;
    int b = bh >> 2, h = bh & 3;
    const char* kbase = (const char*)(k_ws + (size_t)bh * 12288);
    const char* vbase = (const char*)(v_ws + (size_t)bh * 12288);
    #pragma unroll
    for (int it = 0; it < 3; ++it) {
        int byte = it * 8192 + t * 16;
        *(int4*)(Ksh + byte) = *(const int4*)(kbase + byte);
        *(int4*)(Vsh + byte) = *(const int4*)(vbase + byte);
    }
    __syncthreads();
    int wid = t >> 6, lane = t & 63, lr = lane & 15, g = lane >> 4;
    const char* qbase = (const char*)(q_ws + (size_t)bh * 12288);
    const float* bbase = bias_f + (size_t)h * 147456;
    bf16x8 qf[3];
    const f32x4* bp[3];
    #pragma unroll
    for (int u = 0; u < 3; ++u) {
        int qtile = wid + u * 8;
        qf[u] = *(const bf16x8*)(qbase + qtile * 1024 + lane * 16);
        bp[u] = (const f32x4*)(bbase + qtile * 6144) + lane;   // [ktile][lane] f32x4
    }
    // prime the bias pipeline (ktiles 0,1)
    f32x4 bcur[3][2];
    #pragma unroll
    for (int u = 0; u < 3; ++u) {
        bcur[u][0] = bp[u][0];
        bcur[u][1] = bp[u][64];
    }
    f32x4 oa[3][2] = {};
    float lsum[3] = {0.f, 0.f, 0.f};
    #pragma unroll 1
    for (int kt = 0; kt < 4; ++kt) {
        #pragma unroll
        for (int tt = 0; tt < 3; ++tt) {
            int k0t = kt * 6 + tt * 2;
            // prefetch next tt's bias (final iteration reads <=2KB past bias into W2
            // region — allocated workspace, value discarded)
            int knext = k0t + 2;
            f32x4 bnext[3][2];
            #pragma unroll
            for (int u = 0; u < 3; ++u) {
                bnext[u][0] = bp[u][knext * 64];
                bnext[u][1] = bp[u][(knext + 1) * 64];
            }
            bf16x8 kf0 = *(const bf16x8*)(Ksh + k0t * 1024 + lane * 16);
            bf16x8 kf1 = *(const bf16x8*)(Ksh + (k0t + 1) * 1024 + lane * 16);
            bf16x8 pf[3];
            #pragma unroll
            for (int u = 0; u < 3; ++u) {
                f32x4 a0 = __builtin_amdgcn_mfma_f32_16x16x32_bf16(kf0, qf[u], bcur[u][0], 0, 0, 0);
                f32x4 a1 = __builtin_amdgcn_mfma_f32_16x16x32_bf16(kf1, qf[u], bcur[u][1], 0, 0, 0);
                #pragma unroll
                for (int i = 0; i < 4; ++i) {
                    float p0 = fast_pexp(a0[i]);
                    float p1 = fast_pexp(a1[i]);
                    lsum[u] += p0 + p1;
                    pf[u][i]     = (bf16)p0;
                    pf[u][4 + i] = (bf16)p1;
                }
            }
            const char* vb = Vsh + (kt * 3 + tt) * 2048 + lane * 16;
            bf16x8 vf0 = *(const bf16x8*)(vb);
            bf16x8 vf1 = *(const bf16x8*)(vb + 1024);
            #pragma unroll
            for (int u = 0; u < 3; ++u) {
                oa[u][0] = __builtin_amdgcn_mfma_f32_16x16x32_bf16(pf[u], vf0, oa[u][0], 0, 0, 0);
                oa[u][1] = __builtin_amdgcn_mfma_f32_16x16x32_bf16(pf[u], vf1, oa[u][1], 0, 0, 0);
            }
            #pragma unroll
            for (int u = 0; u < 3; ++u) {
                bcur[u][0] = bnext[u][0];
                bcur[u][1] = bnext[u][1];
            }
        }
    }
    #pragma unroll
    for (int u = 0; u < 3; ++u) {
        float l = lsum[u];
        l += __shfl_xor(l, 16);
        l += __shfl_xor(l, 32);
        float inv = 1.0f / l;
        float invq[4];
        #pragma unroll
        for (int i = 0; i < 4; ++i) invq[i] = __shfl(inv, 4 * g + i);
        int q0 = (wid + u * 8) * 16;
        #pragma unroll
        for (int dt = 0; dt < 2; ++dt)
            #pragma unroll
            for (int i = 0; i < 4; ++i)
                o_ws[((size_t)b * 384 + q0 + 4 * g + i) * 128 + h * 32 + dt * 16 + lr] = (bf16)(oa[u][dt][i] * invq[i]);
    }
}

// ---------------- k4: out = (o * sigmoid(g)) @ o_w^T, 512 thr BM=128 ----------------
__global__ __launch_bounds__(512, 2) void k4_out(const bf16* __restrict__ o_ws,
                                                 const bf16* __restrict__ g_ws,
                                                 const bf16* __restrict__ o_wb,
                                                 float* __restrict__ out) {
    __shared__ __align__(16) char smem[128 * 272 + 128 * 272];
    char* As = smem;
    char* Bs = smem + 128 * 272;
    int t = threadIdx.x;
    int m0 = blockIdx.x * 128;
    #pragma unroll
    for (int it = 0; it < 4; ++it) {
        int byte = it * 8192 + t * 16;
        int row = byte >> 8, colb = byte & 255;
        bf16x8 o8 = *(const bf16x8*)((const char*)o_ws + (size_t)(m0 + row) * 256 + colb);
        bf16x8 g8 = *(const bf16x8*)((const char*)g_ws + (size_t)(m0 + row) * 256 + colb);
        bf16x8 a8;
        #pragma unroll
        for (int j = 0; j < 8; ++j) {
            float ov = (float)o8[j], gv = (float)g8[j];
            a8[j] = (bf16)(ov / (1.0f + __expf(-gv)));
        }
        *(bf16x8*)(As + row * 272 + colb) = a8;
    }
    #pragma unroll
    for (int it = 0; it < 4; ++it) {
        int byte = it * 8192 + t * 16;
        int row = byte >> 8, colb = byte & 255;
        *(int4*)(Bs + row * 272 + colb) = *(const int4*)((const char*)o_wb + (size_t)row * 256 + colb);
    }
    __syncthreads();
    int wid = t >> 6, lane = t & 63, lr = lane & 15, g = lane >> 4;
    int wm = wid >> 1, wn = wid & 1;          // 8 waves: 4x2 grid of 32x64 tiles
    f32x4 acc[2][4] = {};
    #pragma unroll
    for (int ks = 0; ks < 4; ++ks) {
        bf16x8 af[2], bfr[4];
        #pragma unroll
        for (int mt = 0; mt < 2; ++mt)
            af[mt] = *(const bf16x8*)(As + (wm * 32 + mt * 16 + lr) * 272 + ks * 64 + g * 16);
        #pragma unroll
        for (int nt = 0; nt < 4; ++nt)
            bfr[nt] = *(const bf16x8*)(Bs + (wn * 64 + nt * 16 + lr) * 272 + ks * 64 + g * 16);
        #pragma unroll
        for (int mt = 0; mt < 2; ++mt)
            #pragma unroll
            for (int nt = 0; nt < 4; ++nt)
                acc[mt][nt] = __builtin_amdgcn_mfma_f32_16x16x32_bf16(af[mt], bfr[nt], acc[mt][nt], 0, 0, 0);
    }
    #pragma unroll
    for (int mt = 0; mt < 2; ++mt)
        #pragma unroll
        for (int nt = 0; nt < 4; ++nt)
            #pragma unroll
            for (int i = 0; i < 4; ++i) {
                int m = m0 + wm * 32 + mt * 16 + g * 4 + i;
                int n = wn * 64 + nt * 16 + lr;
                out[(size_t)m * 128 + n] = acc[mt][nt][i];
            }
}

extern "C" void kernel_launch(void* const* d_in, const int* in_sizes, int n_in,
                              void* d_out, int out_size, void* d_ws, size_t ws_size,
                              hipStream_t stream) {
    const float* x      = (const float*)d_in[0];
    const float* mask   = (const float*)d_in[1];
    const float* ln_w   = (const float*)d_in[2];
    const float* ln_b   = (const float*)d_in[3];
    const float* bias_w = (const float*)d_in[4];
    const float* qkv_w  = (const float*)d_in[5];
    const float* g_w    = (const float*)d_in[6];
    const float* o_w    = (const float*)d_in[7];
    char* ws = (char*)d_ws;
    bf16*  ln_ws  = (bf16*)(ws + OFF_LN);
    bf16*  q_ws   = (bf16*)(ws + OFF_Q);
    bf16*  k_ws   = (bf16*)(ws + OFF_K);
    bf16*  v_ws   = (bf16*)(ws + OFF_V);
    bf16*  g_ws   = (bf16*)(ws + OFF_G);
    float* bias_f = (float*)(ws + OFF_BIAS);
    bf16*  W2     = (bf16*)(ws + OFF_W2);
    bf16*  o_wb   = (bf16*)(ws + OFF_OWB);
    bf16*  o_ws   = ln_ws;   // alias: ln dead after k2
    float* out    = (float*)d_out;

    k0_convert<<<dim3(320), dim3(256), 0, stream>>>(qkv_w, g_w, o_w, W2, o_wb);
    k1_ln<<<dim3(MTOT / 8), dim3(256), 0, stream>>>(x, ln_w, ln_b, bias_w, mask, ln_ws, bias_f);
    k2_proj<<<dim3(MTOT / 128 * 4), dim3(512), 0, stream>>>(ln_ws, W2, q_ws, k_ws, v_ws, g_ws);
    k3_attn<<<dim3(S_ * 4), dim3(512), 0, stream>>>(q_ws, k_ws, v_ws, bias_f, o_ws);
    k4_out<<<dim3(MTOT / 128), dim3(512), 0, stream>>>(o_ws, g_ws, o_wb, out);
}